// Round 1
// baseline (4715.149 us; speedup 1.0000x reference)
//
#include <hip/hip_runtime.h>
#include <hip/hip_bf16.h>

#define B   64
#define H   512
#define V   32000
#define T   38
#define G4  2048      // 4*H
#define NSTEP 37      // T-1
#define VT  64        // v-tile per logits block
#define KC  64        // k-chunk
#define LDP 68        // LDS pad: 68*4B = 272B, 16B-aligned rows, banks spread

__device__ __forceinline__ float sigf(float x){ return 1.0f/(1.0f + expf(-x)); }

__device__ __forceinline__ unsigned int fkey(float x){
  unsigned int u = __float_as_uint(x);
  return (u & 0x80000000u) ? ~u : (u | 0x80000000u);
}

// ---------------- init: h/c parity0 = feat^T per layer; packed argmax slots = 0
__global__ __launch_bounds__(256) void k_init_state(const float* __restrict__ feat,
                                                    float* __restrict__ hT, float* __restrict__ cT,
                                                    unsigned long long* __restrict__ packed){
  int idx = blockIdx.x*blockDim.x + threadIdx.x;     // covers 3*H*B = 98304
  if (idx < 3*H*B){
    int b = idx & (B-1);
    int k = (idx >> 6) & (H-1);
    float v = feat[(size_t)b*H + k];
    hT[idx] = v;          // parity 0, layer l = idx>>15
    cT[idx] = v;
  }
  if (idx < NSTEP*B) packed[idx] = 0ULL;
}

// ---------------- gfeat[gate][j][b] = feat[b] . W_ih0[gate*H+j][0:H] + b_ih[0][r] + b_hh[0][r]
__global__ __launch_bounds__(256) void k_gfeat(const float* __restrict__ feat,
                                               const float* __restrict__ Wih0,
                                               const float* __restrict__ b_ih,
                                               const float* __restrict__ b_hh,
                                               float* __restrict__ gfeatT){
  int j = blockIdx.x;            // 0..H-1
  int b = threadIdx.x;           // 0..63
  int gate = threadIdx.y;        // 0..3
  int r = gate*H + j;
  const float* w = Wih0 + (size_t)r*(2*H);   // feat columns [0,H)
  const float* x = feat + (size_t)b*H;
  float acc = 0.f;
  #pragma unroll 4
  for (int k=0;k<H;k++) acc = fmaf(w[k], x[k], acc);
  gfeatT[((size_t)gate*H + j)*B + b] = acc + b_ih[r] + b_hh[r];
}

// ---------------- output column 0: (embed[SOS] . W_proj[v]) + b_proj[v], broadcast over b
__global__ __launch_bounds__(256) void k_row0(const float* __restrict__ embed_,
                                              const float* __restrict__ Wp,
                                              const float* __restrict__ bp,
                                              float* __restrict__ dst, int mode){
  int v = blockIdx.x*blockDim.x + threadIdx.x;
  if (v >= V) return;
  const float4* e = (const float4*)embed_;                 // row 0 = SOS
  const float4* w = (const float4*)(Wp + (size_t)v*H);
  float acc = 0.f;
  #pragma unroll 4
  for (int k=0;k<H/4;k++){
    float4 a = e[k], c = w[k];
    acc += a.x*c.x + a.y*c.y + a.z*c.z + a.w*c.w;
  }
  acc += bp[v];
  if (mode == 0){            // staged: dst = stage (t=0 plane), [b][v]
    for (int b=0;b<B;b++) dst[(size_t)b*V + v] = acc;
  } else {                   // fallback: dst = out, [b][v][t=0]
    for (int b=0;b<B;b++) dst[((size_t)b*V + v)*T] = acc;
  }
}

// ---------------- one LSTM layer for one step.
// block (64 b, 4 ks): ks 0..1 -> input-to-hidden K halves, ks 2..3 -> hidden-to-hidden halves.
__global__ __launch_bounds__(256) void k_lstm(int layer, int s,
    const float* __restrict__ Wih, const float* __restrict__ Whh,
    const float* __restrict__ bias_ih, const float* __restrict__ bias_hh, // pre-offset by layer (unused layer0)
    const float* __restrict__ gfeatT,      // layer0
    const float* __restrict__ embed_,      // layer0
    const unsigned long long* __restrict__ packedPrev, // layer0, s>0 (pre-offset to step s-1)
    const float* __restrict__ xLowerT,     // layer>=1: new h of lower layer [H][B]
    const float* __restrict__ hOldT,       // own layer old h [H][B]
    float* __restrict__ hNewT,             // own layer new h [H][B]
    float* __restrict__ cT_)               // own layer c [H][B] (in-place)
{
  const int j  = blockIdx.x;     // gate-group row 0..H-1
  const int b  = threadIdx.x;    // 0..63
  const int ks = threadIdx.y;    // 0..3
  __shared__ float part[4][4][B];

  const int kbase = (ks & 1)*256;
  const float *w0,*w1,*w2,*w3;
  const float* xptr = nullptr;
  const float* eptr = nullptr;

  if (ks < 2){
    if (layer == 0){
      const size_t gs = (size_t)H*(2*H);
      w0 = Wih + (size_t)j*(2*H) + H + kbase;   // emb columns [H,2H)
      w1 = w0 + gs; w2 = w0 + 2*gs; w3 = w0 + 3*gs;
      int er = 0;
      if (s > 0) er = (int)(~(unsigned int)(packedPrev[b] & 0xFFFFFFFFull));
      eptr = embed_ + (size_t)er*H + kbase;
    } else {
      const size_t gs = (size_t)H*H;
      w0 = Wih + (size_t)j*H + kbase;
      w1 = w0 + gs; w2 = w0 + 2*gs; w3 = w0 + 3*gs;
      xptr = xLowerT + (size_t)kbase*B + b;
    }
  } else {
    const size_t gs = (size_t)H*H;
    w0 = Whh + (size_t)j*H + kbase;
    w1 = w0 + gs; w2 = w0 + 2*gs; w3 = w0 + 3*gs;
    xptr = hOldT + (size_t)kbase*B + b;
  }

  float a0=0.f, a1=0.f, a2=0.f, a3=0.f;
  if (eptr){
    #pragma unroll 4
    for (int k=0;k<256;k++){
      float xv = eptr[k];
      a0 = fmaf(w0[k], xv, a0); a1 = fmaf(w1[k], xv, a1);
      a2 = fmaf(w2[k], xv, a2); a3 = fmaf(w3[k], xv, a3);
    }
  } else {
    #pragma unroll 4
    for (int k=0;k<256;k++){
      float xv = xptr[(size_t)k*B];
      a0 = fmaf(w0[k], xv, a0); a1 = fmaf(w1[k], xv, a1);
      a2 = fmaf(w2[k], xv, a2); a3 = fmaf(w3[k], xv, a3);
    }
  }
  part[ks][0][b]=a0; part[ks][1][b]=a1; part[ks][2][b]=a2; part[ks][3][b]=a3;
  __syncthreads();

  if (ks == 0){
    float g[4];
    #pragma unroll
    for (int gt=0; gt<4; gt++){
      float sum = part[0][gt][b] + part[1][gt][b] + part[2][gt][b] + part[3][gt][b];
      if (layer == 0) sum += gfeatT[((size_t)gt*H + j)*B + b];
      else            sum += bias_ih[gt*H + j] + bias_hh[gt*H + j];
      g[gt] = sum;
    }
    float i_ = sigf(g[0]);
    float f_ = sigf(g[1]);
    float gg = tanhf(g[2]);
    float o_ = sigf(g[3]);
    float cold = cT_[(size_t)j*B + b];
    float c2 = f_*cold + i_*gg;
    float h2 = o_*tanhf(c2);
    cT_[(size_t)j*B + b]  = c2;
    hNewT[(size_t)j*B + b] = h2;
  }
}

// ---------------- logits = h2 . W_proj^T + b_proj; write step plane; fused block+global argmax
__global__ __launch_bounds__(256) void k_logits(
    const float* __restrict__ h2T,        // [H][B]
    const float* __restrict__ Wp,         // [V][H]
    const float* __restrict__ bp,         // [V]
    float* __restrict__ dst, int strideV, int strideB,
    unsigned long long* __restrict__ packedS)
{
  __shared__ float Wt[KC][LDP];           // [k][v-local]
  __shared__ float Xt[KC][LDP];           // [k][b]
  __shared__ unsigned long long red[B][17];

  const int tid = threadIdx.x;
  const int v0  = blockIdx.x * VT;
  const int tv  = tid & 15;               // v-group
  const int tb  = tid >> 4;               // b-group
  const int vr  = tid >> 2;               // staging row 0..63
  const int kq  = tid & 3;                // staging quarter

  float acc[4][4];                        // [bj][vi]
  #pragma unroll
  for (int i=0;i<4;i++)
    #pragma unroll
    for (int q=0;q<4;q++) acc[i][q] = 0.f;

  for (int k0=0; k0<H; k0+=KC){
    __syncthreads();
    const float* wsrc = Wp + (size_t)(v0+vr)*H + k0 + kq*16;
    #pragma unroll
    for (int i=0;i<4;i++){
      float4 w4 = *(const float4*)(wsrc + i*4);
      int kk = kq*16 + i*4;
      Wt[kk+0][vr]=w4.x; Wt[kk+1][vr]=w4.y; Wt[kk+2][vr]=w4.z; Wt[kk+3][vr]=w4.w;
    }
    const float* xsrc = h2T + (size_t)(k0+vr)*B + kq*16;
    #pragma unroll
    for (int i=0;i<4;i++){
      float4 x4 = *(const float4*)(xsrc + i*4);
      int bb = kq*16 + i*4;
      Xt[vr][bb+0]=x4.x; Xt[vr][bb+1]=x4.y; Xt[vr][bb+2]=x4.z; Xt[vr][bb+3]=x4.w;
    }
    __syncthreads();
    #pragma unroll 8
    for (int k=0;k<KC;k++){
      float4 w4 = *(const float4*)&Wt[k][tv<<2];
      float4 x4 = *(const float4*)&Xt[k][tb<<2];
      acc[0][0]=fmaf(x4.x,w4.x,acc[0][0]); acc[0][1]=fmaf(x4.x,w4.y,acc[0][1]);
      acc[0][2]=fmaf(x4.x,w4.z,acc[0][2]); acc[0][3]=fmaf(x4.x,w4.w,acc[0][3]);
      acc[1][0]=fmaf(x4.y,w4.x,acc[1][0]); acc[1][1]=fmaf(x4.y,w4.y,acc[1][1]);
      acc[1][2]=fmaf(x4.y,w4.z,acc[1][2]); acc[1][3]=fmaf(x4.y,w4.w,acc[1][3]);
      acc[2][0]=fmaf(x4.z,w4.x,acc[2][0]); acc[2][1]=fmaf(x4.z,w4.y,acc[2][1]);
      acc[2][2]=fmaf(x4.z,w4.z,acc[2][2]); acc[2][3]=fmaf(x4.z,w4.w,acc[2][3]);
      acc[3][0]=fmaf(x4.w,w4.x,acc[3][0]); acc[3][1]=fmaf(x4.w,w4.y,acc[3][1]);
      acc[3][2]=fmaf(x4.w,w4.z,acc[3][2]); acc[3][3]=fmaf(x4.w,w4.w,acc[3][3]);
    }
  }

  float4 bb4 = *(const float4*)(bp + v0 + (tv<<2));
  float barr[4] = {bb4.x, bb4.y, bb4.z, bb4.w};
  float vals[4][4];
  #pragma unroll
  for (int bj=0;bj<4;bj++)
    #pragma unroll
    for (int vi=0;vi<4;vi++) vals[bj][vi] = acc[bj][vi] + barr[vi];

  if (strideV == 1){
    #pragma unroll
    for (int bj=0;bj<4;bj++){
      int b = (tb<<2)+bj;
      *(float4*)(dst + (size_t)b*strideB + v0 + (tv<<2)) =
          make_float4(vals[bj][0], vals[bj][1], vals[bj][2], vals[bj][3]);
    }
  } else {
    #pragma unroll
    for (int bj=0;bj<4;bj++){
      int b = (tb<<2)+bj;
      #pragma unroll
      for (int vi=0;vi<4;vi++)
        dst[(size_t)b*strideB + (size_t)(v0+(tv<<2)+vi)*strideV] = vals[bj][vi];
    }
  }

  // block-local argmax -> one atomic per (block,b)
  #pragma unroll
  for (int bj=0;bj<4;bj++){
    float m = vals[bj][0]; int mi = v0+(tv<<2);
    #pragma unroll
    for (int vi=1;vi<4;vi++){
      if (vals[bj][vi] > m){ m = vals[bj][vi]; mi = v0+(tv<<2)+vi; }
    }
    unsigned long long key = ((unsigned long long)fkey(m)<<32)
                           | (unsigned long long)(unsigned int)(~(unsigned int)mi);
    red[(tb<<2)+bj][tv] = key;
  }
  __syncthreads();
  if (tid < B){
    unsigned long long best = red[tid][0];
    #pragma unroll
    for (int t2=1;t2<16;t2++){ unsigned long long k2 = red[tid][t2]; if (k2 > best) best = k2; }
    atomicMax(packedS + tid, best);
  }
}

// ---------------- stage[t][b][v] -> out[b][v][t]
__global__ __launch_bounds__(256) void k_transpose(const float* __restrict__ stage,
                                                   float* __restrict__ out){
  int idx = blockIdx.x*blockDim.x + threadIdx.x;   // over B*V, v fastest
  float vals[T];
  #pragma unroll
  for (int t=0;t<T;t++) vals[t] = stage[(size_t)t*B*V + idx];
  float2* o = (float2*)(out + (size_t)idx*T);
  #pragma unroll
  for (int t=0;t<T;t+=2) o[t>>1] = make_float2(vals[t], vals[t+1]);
}

extern "C" void kernel_launch(void* const* d_in, const int* in_sizes, int n_in,
                              void* d_out, int out_size, void* d_ws, size_t ws_size,
                              hipStream_t stream){
  const float* feat      = (const float*)d_in[0];
  const float* W_ih0     = (const float*)d_in[1];
  const float* W_hh0     = (const float*)d_in[2];
  const float* W_ih_rest = (const float*)d_in[3];
  const float* W_hh_rest = (const float*)d_in[4];
  const float* b_ih      = (const float*)d_in[5];
  const float* b_hh      = (const float*)d_in[6];
  const float* embed     = (const float*)d_in[7];
  const float* W_proj    = (const float*)d_in[8];
  const float* b_proj    = (const float*)d_in[9];
  // inputs 10..15 (attention weights) are mathematically dead: enc is l-uniform
  // so softmax over l is uniform and ctx == feat at every step.
  float* out = (float*)d_out;

  char* ws = (char*)d_ws;
  size_t off = 0;
  float* hT = (float*)(ws + off); off += (size_t)2*3*H*B*4;   // [parity][layer][k][b]
  float* cT = (float*)(ws + off); off += (size_t)3*H*B*4;     // [layer][k][b]
  float* gfeatT = (float*)(ws + off); off += (size_t)4*H*B*4; // [gate][j][b]
  unsigned long long* packed = (unsigned long long*)(ws + off); off += (size_t)NSTEP*B*8;
  off = (off + 255) & ~(size_t)255;
  float* stage = (float*)(ws + off);
  const size_t stageBytes = (size_t)T*B*V*4;
  const bool staged = (ws_size >= off + stageBytes);

  dim3 bl64x4(64,4);
  k_init_state<<<(3*H*B + 255)/256, 256, 0, stream>>>(feat, hT, cT, packed);
  k_gfeat<<<H, bl64x4, 0, stream>>>(feat, W_ih0, b_ih, b_hh, gfeatT);
  if (staged) k_row0<<<(V+255)/256, 256, 0, stream>>>(embed, W_proj, b_proj, stage, 0);
  else        k_row0<<<(V+255)/256, 256, 0, stream>>>(embed, W_proj, b_proj, out, 1);

  const size_t LHB = (size_t)H*B;          // one [H][B] plane
  for (int s=0; s<NSTEP; s++){
    const int p = s & 1, q = p ^ 1;
    float* hOld = hT + (size_t)p*3*LHB;
    float* hNew = hT + (size_t)q*3*LHB;
    const unsigned long long* pk = packed + (size_t)(s>0 ? s-1 : 0)*B;

    k_lstm<<<H, bl64x4, 0, stream>>>(0, s, W_ih0, W_hh0,
        b_ih, b_hh, gfeatT, embed, pk,
        (const float*)nullptr, hOld + 0*LHB, hNew + 0*LHB, cT + 0*LHB);
    k_lstm<<<H, bl64x4, 0, stream>>>(1, s, W_ih_rest, W_hh_rest,
        b_ih + 1*G4, b_hh + 1*G4, (const float*)nullptr, (const float*)nullptr,
        (const unsigned long long*)nullptr,
        hNew + 0*LHB, hOld + 1*LHB, hNew + 1*LHB, cT + 1*LHB);
    k_lstm<<<H, bl64x4, 0, stream>>>(2, s, W_ih_rest + (size_t)G4*H, W_hh_rest + (size_t)G4*H,
        b_ih + 2*G4, b_hh + 2*G4, (const float*)nullptr, (const float*)nullptr,
        (const unsigned long long*)nullptr,
        hNew + 1*LHB, hOld + 2*LHB, hNew + 2*LHB, cT + 2*LHB);

    if (staged)
      k_logits<<<V/VT, 256, 0, stream>>>(hNew + 2*LHB, W_proj, b_proj,
          stage + (size_t)(s+1)*B*V, 1, V, packed + (size_t)s*B);
    else
      k_logits<<<V/VT, 256, 0, stream>>>(hNew + 2*LHB, W_proj, b_proj,
          out + (s+1), T, V*T, packed + (size_t)s*B);
  }

  if (staged) k_transpose<<<(B*V)/256, 256, 0, stream>>>(stage, out);
}